// Round 14
// baseline (65.296 us; speedup 1.0000x reference)
//
#include <hip/hip_runtime.h>

// Problem constants (from reference): D=128, P=8, Q=40 (NUM_NEGATIVES=5*P)
#define DIMS   128
#define PNUM   8
#define QNUM   40
#define NBR    48   // P + Q
#define WAVES_PER_BLOCK 4

typedef float f32x4 __attribute__((ext_vector_type(4)));

// ---------------------------------------------------------------------------
// Kernel 0: convert x fp32 -> fp8 e4m3 (OCP), plain row-major. Row = 128 B.
// (proven R5/R10)
// ---------------------------------------------------------------------------
__global__ __launch_bounds__(256) void convert_f32_to_f8(
    const float* __restrict__ x, unsigned int* __restrict__ x8, int n8)
{
    const int stride = gridDim.x * blockDim.x;
    for (int i = blockIdx.x * blockDim.x + threadIdx.x; i < n8; i += stride) {
        const float4 v0 = reinterpret_cast<const float4*>(x)[2 * i];
        const float4 v1 = reinterpret_cast<const float4*>(x)[2 * i + 1];
        unsigned int a = __builtin_amdgcn_cvt_pk_fp8_f32(v0.x, v0.y, 0u, false);
        a = __builtin_amdgcn_cvt_pk_fp8_f32(v0.z, v0.w, a, true);
        unsigned int b = __builtin_amdgcn_cvt_pk_fp8_f32(v1.x, v1.y, 0u, false);
        b = __builtin_amdgcn_cvt_pk_fp8_f32(v1.z, v1.w, b, true);
        uint2 o; o.x = a; o.y = b;
        reinterpret_cast<uint2*>(x8)[i] = o;
    }
}

// ---------------------------------------------------------------------------
// Shared epilogue (fast transcendentals): per-lane sigmoid score s (lane<48)
// -> this node's loss v. Needs score of neighbor `lane` in lane `lane`.
// ---------------------------------------------------------------------------
__device__ __forceinline__ float node_epilogue(float s, int lane, int N, int h)
{
    float pair_part = 0.0f;
    if (lane < NBR) {
        const float sp = __logf(1.0f + __expf(s));   // softplus(s), s in (0,1)
        pair_part = (lane < PNUM) ? (sp - s) : sp;   // label 1 vs 0
    }
    // Group-of-8 sums: group 0 = pos mean, groups 1..5 = neg tuple means
    float gs = s;
    gs += __shfl_xor(gs, 1);
    gs += __shfl_xor(gs, 2);
    gs += __shfl_xor(gs, 4);

    float tuple_part = 0.0f;
    if ((lane & 7) == 0 && lane < NBR) {
        const float t  = gs * 0.125f;
        const float sp = __logf(1.0f + __expf(t));
        tuple_part = (lane == 0) ? (sp - t) : sp;
    }
    const float pair_scale  = 1.0f / (48.0f * (float)N);
    const float tuple_scale = 1.0f / (6.0f  * (float)(N - h));
    return pair_part * pair_scale + tuple_part * tuple_scale;
}

// ---------------------------------------------------------------------------
// Kernel 1 (wave-per-node MFMA): one wave per node; the wave's 48 dots are
// computed by 12 fp8 MFMAs on the (otherwise idle) matrix pipe.
//   A = own row broadcast into all 16 A-rows  => every D-row = wanted dots.
//   Tile g (g=0..2) covers neighbors g*16..g*16+15 as B columns.
//   Lane l holds D col (l&15) of every tile => score of neighbor l is in
//   acc_{l>>4}[0] of lane l. No LDS staging, no butterflies, no extraction.
// K-mapping: lane q=l>>4 supplies bytes [q*32+kb*8 .. +8) of its row for
// MFMA kb; A and B use identical addressing so the HW k-permutation cancels
// and the 4-MFMA sum is the exact 128-dot (validated family: R6/R7).
// Gathers: 2 x 16B loads per tile touch 16 lines (1 line/row, minimal TA).
// ---------------------------------------------------------------------------
__global__ __launch_bounds__(256) void node_loss_mfma_wave(
    const unsigned char* __restrict__ x8,   // fp8 matrix, 128 B per row
    const int*           __restrict__ pos_idx,
    const int*           __restrict__ neg_idx,
    const int*           __restrict__ h_ptr,
    float*               __restrict__ ws,
    int N)
{
    __shared__ float wsum[WAVES_PER_BLOCK];

    const int wave = threadIdx.x >> 6;
    const int lane = threadIdx.x & 63;
    const int col  = lane & 15;    // neighbor-within-tile (B column)
    const int q    = lane >> 4;    // k-quarter (bytes q*32..+32 of a row)
    const int node = blockIdx.x * WAVES_PER_BLOCK + wave;

    const int h = *h_ptr;          // scalar broadcast, off the critical chain

    float v = 0.0f;
    if (node < N) {
        // (1) idx loads: tile 0 mixes pos/neg, tiles 1-2 are neg.
        const int nb0 = (col < PNUM) ? pos_idx[node * PNUM + col]
                                     : neg_idx[node * QNUM + (col - PNUM)];
        const int nb1 = neg_idx[node * QNUM + 8 + col];
        const int nb2 = neg_idx[node * QNUM + 24 + col];

        // (2) own-row fragments (address depends only on q -> broadcast).
        const unsigned char* ap = x8 + (size_t)node * DIMS + q * 32;
        const ulonglong2 a01 = *reinterpret_cast<const ulonglong2*>(ap);
        const ulonglong2 a23 = *reinterpret_cast<const ulonglong2*>(ap + 16);

        // (3) gather loads: all 6 issued before any MFMA (in flight together).
        const unsigned char* b0p = x8 + (size_t)nb0 * DIMS + q * 32;
        const unsigned char* b1p = x8 + (size_t)nb1 * DIMS + q * 32;
        const unsigned char* b2p = x8 + (size_t)nb2 * DIMS + q * 32;
        const ulonglong2 b0a = *reinterpret_cast<const ulonglong2*>(b0p);
        const ulonglong2 b0b = *reinterpret_cast<const ulonglong2*>(b0p + 16);
        const ulonglong2 b1a = *reinterpret_cast<const ulonglong2*>(b1p);
        const ulonglong2 b1b = *reinterpret_cast<const ulonglong2*>(b1p + 16);
        const ulonglong2 b2a = *reinterpret_cast<const ulonglong2*>(b2p);
        const ulonglong2 b2b = *reinterpret_cast<const ulonglong2*>(b2p + 16);

        // (4) 12 MFMAs: 3 independent chains of depth 4 (interleaved).
        f32x4 acc0 = {0.f, 0.f, 0.f, 0.f};
        f32x4 acc1 = {0.f, 0.f, 0.f, 0.f};
        f32x4 acc2 = {0.f, 0.f, 0.f, 0.f};
        acc0 = __builtin_amdgcn_mfma_f32_16x16x32_fp8_fp8(
            (long long)a01.x, (long long)b0a.x, acc0, 0, 0, 0);
        acc1 = __builtin_amdgcn_mfma_f32_16x16x32_fp8_fp8(
            (long long)a01.x, (long long)b1a.x, acc1, 0, 0, 0);
        acc2 = __builtin_amdgcn_mfma_f32_16x16x32_fp8_fp8(
            (long long)a01.x, (long long)b2a.x, acc2, 0, 0, 0);
        acc0 = __builtin_amdgcn_mfma_f32_16x16x32_fp8_fp8(
            (long long)a01.y, (long long)b0a.y, acc0, 0, 0, 0);
        acc1 = __builtin_amdgcn_mfma_f32_16x16x32_fp8_fp8(
            (long long)a01.y, (long long)b1a.y, acc1, 0, 0, 0);
        acc2 = __builtin_amdgcn_mfma_f32_16x16x32_fp8_fp8(
            (long long)a01.y, (long long)b2a.y, acc2, 0, 0, 0);
        acc0 = __builtin_amdgcn_mfma_f32_16x16x32_fp8_fp8(
            (long long)a23.x, (long long)b0b.x, acc0, 0, 0, 0);
        acc1 = __builtin_amdgcn_mfma_f32_16x16x32_fp8_fp8(
            (long long)a23.x, (long long)b1b.x, acc1, 0, 0, 0);
        acc2 = __builtin_amdgcn_mfma_f32_16x16x32_fp8_fp8(
            (long long)a23.x, (long long)b2b.x, acc2, 0, 0, 0);
        acc0 = __builtin_amdgcn_mfma_f32_16x16x32_fp8_fp8(
            (long long)a23.y, (long long)b0b.y, acc0, 0, 0, 0);
        acc1 = __builtin_amdgcn_mfma_f32_16x16x32_fp8_fp8(
            (long long)a23.y, (long long)b1b.y, acc1, 0, 0, 0);
        acc2 = __builtin_amdgcn_mfma_f32_16x16x32_fp8_fp8(
            (long long)a23.y, (long long)b2b.y, acc2, 0, 0, 0);

        // (5) score of neighbor `lane` is in this lane's tile-(lane>>4) acc.
        //     (all D-rows identical since all A-rows are the own row)
        float s = 0.0f;
        if (lane < NBR) {
            const float sc = (q == 0) ? acc0[0] : (q == 1) ? acc1[0] : acc2[0];
            s = __builtin_amdgcn_rcpf(1.0f + __expf(-sc));   // sigmoid
        }
        v = node_epilogue(s, lane, N, h);
    }

    v += __shfl_xor(v, 1);
    v += __shfl_xor(v, 2);
    v += __shfl_xor(v, 4);
    v += __shfl_xor(v, 8);
    v += __shfl_xor(v, 16);
    v += __shfl_xor(v, 32);

    if (lane == 0) wsum[wave] = v;
    __syncthreads();
    if (threadIdx.x == 0)
        ws[blockIdx.x] = wsum[0] + wsum[1] + wsum[2] + wsum[3];
}

// ---------------------------------------------------------------------------
// fp32 fallback (proven) if ws_size can't hold the fp8 copy.
// ---------------------------------------------------------------------------
__global__ __launch_bounds__(256) void node_loss_partial_f32(
    const float* __restrict__ x,
    const int*   __restrict__ pos_idx,
    const int*   __restrict__ neg_idx,
    const int*   __restrict__ h_ptr,
    float*       __restrict__ ws,
    int N)
{
    __shared__ float xn_sh[WAVES_PER_BLOCK][DIMS];
    __shared__ float wsum[WAVES_PER_BLOCK];

    const int wave = threadIdx.x >> 6;
    const int lane = threadIdx.x & 63;
    const int node = blockIdx.x * WAVES_PER_BLOCK + wave;

    if (node < N && lane < 32) {
        const float4* row = reinterpret_cast<const float4*>(x + (size_t)node * DIMS);
        reinterpret_cast<float4*>(xn_sh[wave])[lane] = row[lane];
    }
    __syncthreads();

    float v = 0.0f;
    if (node < N) {
        float s = 0.0f;
        if (lane < NBR) {
            const int nb = (lane < PNUM)
                ? pos_idx[node * PNUM + lane]
                : neg_idx[node * QNUM + (lane - PNUM)];
            const float4* nrow = reinterpret_cast<const float4*>(x + (size_t)nb * DIMS);
            const float4* xn4  = reinterpret_cast<const float4*>(xn_sh[wave]);
            float acc = 0.0f;
#pragma unroll
            for (int t = 0; t < DIMS / 4; ++t) {
                const float4 a = xn4[t];
                const float4 b = nrow[t];
                acc += a.x * b.x + a.y * b.y + a.z * b.z + a.w * b.w;
            }
            s = 1.0f / (1.0f + expf(-acc));
        }
        v = node_epilogue(s, lane, N, *h_ptr);
    }

    v += __shfl_xor(v, 1);
    v += __shfl_xor(v, 2);
    v += __shfl_xor(v, 4);
    v += __shfl_xor(v, 8);
    v += __shfl_xor(v, 16);
    v += __shfl_xor(v, 32);

    if (lane == 0) wsum[wave] = v;
    __syncthreads();
    if (threadIdx.x == 0)
        ws[blockIdx.x] = wsum[0] + wsum[1] + wsum[2] + wsum[3];
}

// ---------------------------------------------------------------------------
// Kernel 2: deterministic single-block reduction of per-block partials.
// ---------------------------------------------------------------------------
__global__ __launch_bounds__(256) void reduce_final(
    const float* __restrict__ ws, float* __restrict__ out, int nparts)
{
    __shared__ float sm[WAVES_PER_BLOCK];
    float acc = 0.0f;
    for (int i = threadIdx.x; i < nparts; i += 256) acc += ws[i];

    acc += __shfl_xor(acc, 1);
    acc += __shfl_xor(acc, 2);
    acc += __shfl_xor(acc, 4);
    acc += __shfl_xor(acc, 8);
    acc += __shfl_xor(acc, 16);
    acc += __shfl_xor(acc, 32);

    const int wave = threadIdx.x >> 6;
    const int lane = threadIdx.x & 63;
    if (lane == 0) sm[wave] = acc;
    __syncthreads();
    if (threadIdx.x == 0)
        out[0] = sm[0] + sm[1] + sm[2] + sm[3];
}

extern "C" void kernel_launch(void* const* d_in, const int* in_sizes, int n_in,
                              void* d_out, int out_size, void* d_ws, size_t ws_size,
                              hipStream_t stream) {
    const float* x   = (const float*)d_in[0];
    const int*   pos = (const int*)d_in[1];
    const int*   neg = (const int*)d_in[2];
    const int*   h   = (const int*)d_in[3];

    const int N = in_sizes[0] / DIMS;  // 50000
    const int nblocks = (N + WAVES_PER_BLOCK - 1) / WAVES_PER_BLOCK;

    const size_t x8_bytes = (size_t)N * DIMS;  // 6.4 MB (1 B/elem)
    const size_t need     = x8_bytes + (size_t)nblocks * sizeof(float);

    if (ws_size >= need) {
        unsigned char* x8 = (unsigned char*)d_ws;
        float* partials   = (float*)((char*)d_ws + x8_bytes);  // 128B-aligned
        const int n8 = N * DIMS / 8;
        convert_f32_to_f8<<<2048, 256, 0, stream>>>(x, (unsigned int*)x8, n8);
        node_loss_mfma_wave<<<nblocks, 256, 0, stream>>>(x8, pos, neg, h, partials, N);
        reduce_final<<<1, 256, 0, stream>>>(partials, (float*)d_out, nblocks);
    } else {
        float* partials = (float*)d_ws;
        node_loss_partial_f32<<<nblocks, 256, 0, stream>>>(x, pos, neg, h, partials, N);
        reduce_final<<<1, 256, 0, stream>>>(partials, (float*)d_out, nblocks);
    }
}

// Round 15
// 62.711 us; speedup vs baseline: 1.0412x; 1.0412x over previous
//
#include <hip/hip_runtime.h>

// Problem constants (from reference): D=128, P=8, Q=40 (NUM_NEGATIVES=5*P)
#define DIMS   128
#define PNUM   8
#define QNUM   40
#define NBR    48   // P + Q
#define WPB    4    // waves per block

typedef float f2 __attribute__((ext_vector_type(2)));

// ---------------------------------------------------------------------------
// Kernel 0: convert x fp32 -> fp8 e4m3 (OCP). Row = 128 B. (proven R5/R10)
// ---------------------------------------------------------------------------
__global__ __launch_bounds__(256) void convert_f32_to_f8(
    const float* __restrict__ x, unsigned int* __restrict__ x8, int n8)
{
    const int stride = gridDim.x * blockDim.x;
    for (int i = blockIdx.x * blockDim.x + threadIdx.x; i < n8; i += stride) {
        const float4 v0 = reinterpret_cast<const float4*>(x)[2 * i];
        const float4 v1 = reinterpret_cast<const float4*>(x)[2 * i + 1];
        unsigned int a = __builtin_amdgcn_cvt_pk_fp8_f32(v0.x, v0.y, 0u, false);
        a = __builtin_amdgcn_cvt_pk_fp8_f32(v0.z, v0.w, a, true);
        unsigned int b = __builtin_amdgcn_cvt_pk_fp8_f32(v1.x, v1.y, 0u, false);
        b = __builtin_amdgcn_cvt_pk_fp8_f32(v1.z, v1.w, b, true);
        uint2 o; o.x = a; o.y = b;
        reinterpret_cast<uint2*>(x8)[i] = o;
    }
}

// ---------------------------------------------------------------------------
// Per-lane epilogue terms for one node (fast transcendentals, proven R10).
// ---------------------------------------------------------------------------
__device__ __forceinline__ float node_epilogue(float s, int lane, int N, int h)
{
    float pair_part = 0.0f;
    if (lane < NBR) {
        const float sp = __logf(1.0f + __expf(s));   // softplus(s)
        pair_part = (lane < PNUM) ? (sp - s) : sp;
    }
    float gs = s;
    gs += __shfl_xor(gs, 1);
    gs += __shfl_xor(gs, 2);
    gs += __shfl_xor(gs, 4);

    float tuple_part = 0.0f;
    if ((lane & 7) == 0 && lane < NBR) {
        const float t  = gs * 0.125f;
        const float sp = __logf(1.0f + __expf(t));
        tuple_part = (lane == 0) ? (sp - t) : sp;
    }
    const float pair_scale  = 1.0f / (48.0f * (float)N);
    const float tuple_scale = 1.0f / (6.0f  * (float)(N - h));
    return pair_part * pair_scale + tuple_part * tuple_scale;
}

// ---------------------------------------------------------------------------
// Kernel 1 (persistent waves, 3-stage software pipeline): 1024 blocks, each
// wave grid-strides over ~12 nodes. While computing node i, node i+1's 6
// gathers are in flight and node i+2's idx/own loads issue post-compute.
// Dot core = R10's proven fp8 8-lane-cooperative structure.
// ---------------------------------------------------------------------------
#define IDXLOAD(NB, ND)                                                       \
    do {                                                                      \
        NB[0] = pos_idx[(ND) * PNUM + grp];                                   \
        _Pragma("unroll")                                                     \
        for (int p_ = 1; p_ < 6; ++p_)                                        \
            NB[p_] = neg_idx[(ND) * QNUM + (p_ - 1) * 8 + grp];               \
    } while (0)

#define OWNLOAD(OWN, ND)                                                      \
    do {                                                                      \
        const float4* o_ =                                                    \
            reinterpret_cast<const float4*>(x + (size_t)(ND) * DIMS) + sub * 4;\
        OWN[0] = o_[0]; OWN[1] = o_[1]; OWN[2] = o_[2]; OWN[3] = o_[3];       \
    } while (0)

#define GATHER(Q, NB)                                                         \
    do {                                                                      \
        _Pragma("unroll")                                                     \
        for (int p_ = 0; p_ < 6; ++p_)                                        \
            Q[p_] = *reinterpret_cast<const uint4*>(                          \
                x8 + (size_t)NB[p_] * 32 + sub * 4);                          \
    } while (0)

#define COMPUTE(Q, OWN)                                                       \
    do {                                                                      \
        f2 A2[8];                                                             \
        A2[0] = f2{OWN[0].x, OWN[0].y}; A2[1] = f2{OWN[0].z, OWN[0].w};       \
        A2[2] = f2{OWN[1].x, OWN[1].y}; A2[3] = f2{OWN[1].z, OWN[1].w};       \
        A2[4] = f2{OWN[2].x, OWN[2].y}; A2[5] = f2{OWN[2].z, OWN[2].w};       \
        A2[6] = f2{OWN[3].x, OWN[3].y}; A2[7] = f2{OWN[3].z, OWN[3].w};       \
        _Pragma("unroll")                                                     \
        for (int p_ = 0; p_ < 6; ++p_) {                                      \
            f2 acc2 = {0.0f, 0.0f};                                           \
            acc2 += __builtin_amdgcn_cvt_pk_f32_fp8(Q[p_].x, false) * A2[0];  \
            acc2 += __builtin_amdgcn_cvt_pk_f32_fp8(Q[p_].x, true)  * A2[1];  \
            acc2 += __builtin_amdgcn_cvt_pk_f32_fp8(Q[p_].y, false) * A2[2];  \
            acc2 += __builtin_amdgcn_cvt_pk_f32_fp8(Q[p_].y, true)  * A2[3];  \
            acc2 += __builtin_amdgcn_cvt_pk_f32_fp8(Q[p_].z, false) * A2[4];  \
            acc2 += __builtin_amdgcn_cvt_pk_f32_fp8(Q[p_].z, true)  * A2[5];  \
            acc2 += __builtin_amdgcn_cvt_pk_f32_fp8(Q[p_].w, false) * A2[6];  \
            acc2 += __builtin_amdgcn_cvt_pk_f32_fp8(Q[p_].w, true)  * A2[7];  \
            float acc_ = acc2[0] + acc2[1];                                   \
            acc_ += __shfl_xor(acc_, 1);                                      \
            acc_ += __shfl_xor(acc_, 2);                                      \
            acc_ += __shfl_xor(acc_, 4);                                      \
            if (sub == 0) scores_sh[wave][p_ * 8 + grp] = acc_;               \
        }                                                                     \
        float s_ = 0.0f;                                                      \
        if (lane < NBR) {                                                     \
            const float sc_ = scores_sh[wave][lane];                          \
            s_ = __builtin_amdgcn_rcpf(1.0f + __expf(-sc_));                  \
        }                                                                     \
        vacc += node_epilogue(s_, lane, N, h);                                \
    } while (0)

__global__ __launch_bounds__(256) void node_loss_persist(
    const float*        __restrict__ x,
    const unsigned int* __restrict__ x8,
    const int*          __restrict__ pos_idx,
    const int*          __restrict__ neg_idx,
    const int*          __restrict__ h_ptr,
    float*              __restrict__ ws,
    int N)
{
    __shared__ float scores_sh[WPB][NBR];
    __shared__ float wsum[WPB];

    const int wave = threadIdx.x >> 6;
    const int lane = threadIdx.x & 63;
    const int sub  = lane & 7;
    const int grp  = lane >> 3;
    const int gs_  = gridDim.x * WPB;                 // wave stride over nodes
    const int h    = *h_ptr;

    float vacc = 0.0f;

    int C = blockIdx.x * WPB + wave;                  // current node

    int    nbA[6], nbB[6];
    float4 ownA[4], ownB[4];
    uint4  qA[6], qB[6];

    // Prologue: fill pipeline for C and C+gs_.
    if (C < N) {
        IDXLOAD(nbA, C);
        OWNLOAD(ownA, C);
        if (C + gs_ < N) { IDXLOAD(nbB, C + gs_); OWNLOAD(ownB, C + gs_); }
        GATHER(qA, nbA);
    }

    while (C < N) {
        // ---- body A: compute C (qA/ownA); prefetch C+gs_ gathers, C+2gs_ idx/own
        {
            const int n1 = C + gs_, n2 = C + 2 * gs_;
            if (n1 < N) GATHER(qB, nbB);
            COMPUTE(qA, ownA);
            if (n2 < N) { IDXLOAD(nbA, n2); OWNLOAD(ownA, n2); }
            C = n1;
        }
        if (C >= N) break;
        // ---- body B: symmetric (qB/ownB), prefetch into A-side done above
        {
            const int n1 = C + gs_, n2 = C + 2 * gs_;
            if (n1 < N) GATHER(qA, nbA);
            COMPUTE(qB, ownB);
            if (n2 < N) { IDXLOAD(nbB, n2); OWNLOAD(ownB, n2); }
            C = n1;
        }
    }

    // Once per block: wave reduce + block sum.
    vacc += __shfl_xor(vacc, 1);
    vacc += __shfl_xor(vacc, 2);
    vacc += __shfl_xor(vacc, 4);
    vacc += __shfl_xor(vacc, 8);
    vacc += __shfl_xor(vacc, 16);
    vacc += __shfl_xor(vacc, 32);

    if (lane == 0) wsum[wave] = vacc;
    __syncthreads();
    if (threadIdx.x == 0)
        ws[blockIdx.x] = wsum[0] + wsum[1] + wsum[2] + wsum[3];
}

// ---------------------------------------------------------------------------
// fp32 fallback (proven) if ws_size can't hold the fp8 copy.
// ---------------------------------------------------------------------------
__global__ __launch_bounds__(256) void node_loss_partial_f32(
    const float* __restrict__ x,
    const int*   __restrict__ pos_idx,
    const int*   __restrict__ neg_idx,
    const int*   __restrict__ h_ptr,
    float*       __restrict__ ws,
    int N)
{
    __shared__ float xn_sh[WPB][DIMS];
    __shared__ float wsum[WPB];

    const int wave = threadIdx.x >> 6;
    const int lane = threadIdx.x & 63;
    const int node = blockIdx.x * WPB + wave;

    if (node < N && lane < 32) {
        const float4* row = reinterpret_cast<const float4*>(x + (size_t)node * DIMS);
        reinterpret_cast<float4*>(xn_sh[wave])[lane] = row[lane];
    }
    __syncthreads();

    float v = 0.0f;
    if (node < N) {
        float s = 0.0f;
        if (lane < NBR) {
            const int nb = (lane < PNUM)
                ? pos_idx[node * PNUM + lane]
                : neg_idx[node * QNUM + (lane - PNUM)];
            const float4* nrow = reinterpret_cast<const float4*>(x + (size_t)nb * DIMS);
            const float4* xn4  = reinterpret_cast<const float4*>(xn_sh[wave]);
            float acc = 0.0f;
#pragma unroll
            for (int t = 0; t < DIMS / 4; ++t) {
                const float4 a = xn4[t];
                const float4 b = nrow[t];
                acc += a.x * b.x + a.y * b.y + a.z * b.z + a.w * b.w;
            }
            s = 1.0f / (1.0f + expf(-acc));
        }
        v = node_epilogue(s, lane, N, *h_ptr);
    }

    v += __shfl_xor(v, 1);
    v += __shfl_xor(v, 2);
    v += __shfl_xor(v, 4);
    v += __shfl_xor(v, 8);
    v += __shfl_xor(v, 16);
    v += __shfl_xor(v, 32);

    if (lane == 0) wsum[wave] = v;
    __syncthreads();
    if (threadIdx.x == 0)
        ws[blockIdx.x] = wsum[0] + wsum[1] + wsum[2] + wsum[3];
}

// ---------------------------------------------------------------------------
// Kernel 2: deterministic single-block reduction of per-block partials.
// ---------------------------------------------------------------------------
__global__ __launch_bounds__(256) void reduce_final(
    const float* __restrict__ ws, float* __restrict__ out, int nparts)
{
    __shared__ float sm[WPB];
    float acc = 0.0f;
    for (int i = threadIdx.x; i < nparts; i += 256) acc += ws[i];

    acc += __shfl_xor(acc, 1);
    acc += __shfl_xor(acc, 2);
    acc += __shfl_xor(acc, 4);
    acc += __shfl_xor(acc, 8);
    acc += __shfl_xor(acc, 16);
    acc += __shfl_xor(acc, 32);

    const int wave = threadIdx.x >> 6;
    const int lane = threadIdx.x & 63;
    if (lane == 0) sm[wave] = acc;
    __syncthreads();
    if (threadIdx.x == 0)
        out[0] = sm[0] + sm[1] + sm[2] + sm[3];
}

extern "C" void kernel_launch(void* const* d_in, const int* in_sizes, int n_in,
                              void* d_out, int out_size, void* d_ws, size_t ws_size,
                              hipStream_t stream) {
    const float* x   = (const float*)d_in[0];
    const int*   pos = (const int*)d_in[1];
    const int*   neg = (const int*)d_in[2];
    const int*   h   = (const int*)d_in[3];

    const int N = in_sizes[0] / DIMS;  // 50000

    const size_t x8_bytes = (size_t)N * DIMS;  // 6.4 MB
    const int    PBLOCKS  = 1024;              // fully resident at 4 waves/SIMD
    const size_t need     = x8_bytes + (size_t)PBLOCKS * sizeof(float);

    if (ws_size >= need) {
        unsigned int* x8 = (unsigned int*)d_ws;
        float* partials  = (float*)((char*)d_ws + x8_bytes);  // 128B-aligned
        const int n8 = N * DIMS / 8;
        convert_f32_to_f8<<<2048, 256, 0, stream>>>(x, x8, n8);
        node_loss_persist<<<PBLOCKS, 256, 0, stream>>>(x, x8, pos, neg, h, partials, N);
        reduce_final<<<1, 256, 0, stream>>>(partials, (float*)d_out, PBLOCKS);
    } else {
        float* partials = (float*)d_ws;
        const int nblocks = (N + WPB - 1) / WPB;
        node_loss_partial_f32<<<nblocks, 256, 0, stream>>>(x, pos, neg, h, partials, N);
        reduce_final<<<1, 256, 0, stream>>>(partials, (float*)d_out, nblocks);
    }
}

// Round 16
// 54.322 us; speedup vs baseline: 1.2020x; 1.1544x over previous
//
#include <hip/hip_runtime.h>

// Problem constants (from reference): D=128, P=8, Q=40 (NUM_NEGATIVES=5*P)
#define DIMS   128
#define PNUM   8
#define QNUM   40
#define NBR    48   // P + Q
#define WAVES_PER_BLOCK 4

typedef float f2 __attribute__((ext_vector_type(2)));

// ---------------------------------------------------------------------------
// Kernel 0: convert x fp32 -> fp8 e4m3 (OCP) into workspace. Row = 128 B.
// (proven R5/R10/R13)
// ---------------------------------------------------------------------------
__global__ __launch_bounds__(256) void convert_f32_to_f8(
    const float* __restrict__ x, unsigned int* __restrict__ x8, int n8)
{
    const int stride = gridDim.x * blockDim.x;
    for (int i = blockIdx.x * blockDim.x + threadIdx.x; i < n8; i += stride) {
        const float4 v0 = reinterpret_cast<const float4*>(x)[2 * i];
        const float4 v1 = reinterpret_cast<const float4*>(x)[2 * i + 1];
        unsigned int a = __builtin_amdgcn_cvt_pk_fp8_f32(v0.x, v0.y, 0u, false);
        a = __builtin_amdgcn_cvt_pk_fp8_f32(v0.z, v0.w, a, true);
        unsigned int b = __builtin_amdgcn_cvt_pk_fp8_f32(v1.x, v1.y, 0u, false);
        b = __builtin_amdgcn_cvt_pk_fp8_f32(v1.z, v1.w, b, true);
        uint2 o; o.x = a; o.y = b;
        reinterpret_cast<uint2*>(x8)[i] = o;
    }
}

// ---------------------------------------------------------------------------
// Shared epilogue (fast transcendentals): per-lane sigmoid score s (lane<48)
// -> this node's loss v.
// ---------------------------------------------------------------------------
__device__ __forceinline__ float node_epilogue(float s, int lane, int N, int h)
{
    float pair_part = 0.0f;
    if (lane < NBR) {
        const float sp = __logf(1.0f + __expf(s));   // softplus(s), s in (0,1)
        pair_part = (lane < PNUM) ? (sp - s) : sp;   // label 1 vs 0
    }
    // Group-of-8 sums: group 0 = pos mean, groups 1..5 = neg tuple means
    float gs = s;
    gs += __shfl_xor(gs, 1);
    gs += __shfl_xor(gs, 2);
    gs += __shfl_xor(gs, 4);

    float tuple_part = 0.0f;
    if ((lane & 7) == 0 && lane < NBR) {
        const float t  = gs * 0.125f;
        const float sp = __logf(1.0f + __expf(t));
        tuple_part = (lane == 0) ? (sp - t) : sp;
    }
    const float pair_scale  = 1.0f / (48.0f * (float)N);
    const float tuple_scale = 1.0f / (6.0f  * (float)(N - h));
    return pair_part * pair_scale + tuple_part * tuple_scale;
}

// ---------------------------------------------------------------------------
// Kernel 1 (fp8, 8-lane cooperative, full-MLP, DIRECT idx loads): one wave
// per node. Lane (grp,sub) loads its 6 needed neighbor indices directly
// (broadcast across the 8 sub-lanes of a group) -- no cross-lane shuffle in
// the dependency chain. 6 idx loads + 4 own-row loads + 6 gathers are all
// in flight before any consumption. (proven best: R13, 54.4 us total)
// ---------------------------------------------------------------------------
__global__ __launch_bounds__(256) void node_loss_partial_f8v3(
    const float*        __restrict__ x,
    const unsigned int* __restrict__ x8,   // fp8 matrix, 32 uints per row
    const int*          __restrict__ pos_idx,
    const int*          __restrict__ neg_idx,
    const int*          __restrict__ h_ptr,
    float*              __restrict__ ws,
    int N)
{
    __shared__ float scores_sh[WAVES_PER_BLOCK][NBR];
    __shared__ float wsum[WAVES_PER_BLOCK];

    const int wave = threadIdx.x >> 6;
    const int lane = threadIdx.x & 63;
    const int sub  = lane & 7;     // position within 8-lane row group
    const int grp  = lane >> 3;    // group id: handles rows j = p*8+grp
    const int node = blockIdx.x * WAVES_PER_BLOCK + wave;

    const int h = *h_ptr;          // scalar broadcast, hoisted off the chain

    float v = 0.0f;
    if (node < N) {
        // (1) direct per-lane idx loads: row j = p*8+grp for p=0..5.
        int nb[6];
        nb[0] = pos_idx[node * PNUM + grp];
#pragma unroll
        for (int p = 1; p < 6; ++p)
            nb[p] = neg_idx[node * QNUM + (p - 1) * 8 + grp];

        // (2) own-row fp32 fragment loads (independent, overlap idx latency).
        const float4* own =
            reinterpret_cast<const float4*>(x + (size_t)node * DIMS) + sub * 4;
        const float4 f0 = own[0], f1 = own[1], f2v = own[2], f3 = own[3];

        // (3) all 6 gather loads issued back-to-back into registers.
        uint4 q[6];
#pragma unroll
        for (int p = 0; p < 6; ++p)
            q[p] = *reinterpret_cast<const uint4*>(x8 + (size_t)nb[p] * 32 + sub * 4);

        // Own row as 8 packed float2 (feeds v_pk_fma_f32).
        f2 A2[8];
        A2[0] = f2{f0.x, f0.y};   A2[1] = f2{f0.z, f0.w};
        A2[2] = f2{f1.x, f1.y};   A2[3] = f2{f1.z, f1.w};
        A2[4] = f2{f2v.x, f2v.y}; A2[5] = f2{f2v.z, f2v.w};
        A2[6] = f2{f3.x, f3.y};   A2[7] = f2{f3.z, f3.w};

        // (4) 6 dot cores on buffered data: 8 cvt + 8 packed-fma each.
#pragma unroll
        for (int p = 0; p < 6; ++p) {
            f2 acc2 = {0.0f, 0.0f};
            acc2 += __builtin_amdgcn_cvt_pk_f32_fp8(q[p].x, false) * A2[0];
            acc2 += __builtin_amdgcn_cvt_pk_f32_fp8(q[p].x, true)  * A2[1];
            acc2 += __builtin_amdgcn_cvt_pk_f32_fp8(q[p].y, false) * A2[2];
            acc2 += __builtin_amdgcn_cvt_pk_f32_fp8(q[p].y, true)  * A2[3];
            acc2 += __builtin_amdgcn_cvt_pk_f32_fp8(q[p].z, false) * A2[4];
            acc2 += __builtin_amdgcn_cvt_pk_f32_fp8(q[p].z, true)  * A2[5];
            acc2 += __builtin_amdgcn_cvt_pk_f32_fp8(q[p].w, false) * A2[6];
            acc2 += __builtin_amdgcn_cvt_pk_f32_fp8(q[p].w, true)  * A2[7];
            float acc = acc2[0] + acc2[1];
            // Reduce the 8 partial dots within the group (butterfly).
            acc += __shfl_xor(acc, 1);
            acc += __shfl_xor(acc, 2);
            acc += __shfl_xor(acc, 4);
            if (sub == 0) scores_sh[wave][p * 8 + grp] = acc;
        }

        // Same-wave LDS producer/consumer (DS ops in order, proven R5/R10).
        float s = 0.0f;
        if (lane < NBR) {
            const float sc = scores_sh[wave][lane];
            s = __builtin_amdgcn_rcpf(1.0f + __expf(-sc));   // sigmoid
        }
        v = node_epilogue(s, lane, N, h);
    }

    v += __shfl_xor(v, 1);
    v += __shfl_xor(v, 2);
    v += __shfl_xor(v, 4);
    v += __shfl_xor(v, 8);
    v += __shfl_xor(v, 16);
    v += __shfl_xor(v, 32);

    if (lane == 0) wsum[wave] = v;
    __syncthreads();
    if (threadIdx.x == 0)
        ws[blockIdx.x] = wsum[0] + wsum[1] + wsum[2] + wsum[3];
}

// ---------------------------------------------------------------------------
// fp32 fallback (proven) if ws_size can't hold the fp8 copy.
// ---------------------------------------------------------------------------
__global__ __launch_bounds__(256) void node_loss_partial_f32(
    const float* __restrict__ x,
    const int*   __restrict__ pos_idx,
    const int*   __restrict__ neg_idx,
    const int*   __restrict__ h_ptr,
    float*       __restrict__ ws,
    int N)
{
    __shared__ float xn_sh[WAVES_PER_BLOCK][DIMS];
    __shared__ float wsum[WAVES_PER_BLOCK];

    const int wave = threadIdx.x >> 6;
    const int lane = threadIdx.x & 63;
    const int node = blockIdx.x * WAVES_PER_BLOCK + wave;

    if (node < N && lane < 32) {
        const float4* row = reinterpret_cast<const float4*>(x + (size_t)node * DIMS);
        reinterpret_cast<float4*>(xn_sh[wave])[lane] = row[lane];
    }
    __syncthreads();

    float v = 0.0f;
    if (node < N) {
        float s = 0.0f;
        if (lane < NBR) {
            const int nb = (lane < PNUM)
                ? pos_idx[node * PNUM + lane]
                : neg_idx[node * QNUM + (lane - PNUM)];
            const float4* nrow = reinterpret_cast<const float4*>(x + (size_t)nb * DIMS);
            const float4* xn4  = reinterpret_cast<const float4*>(xn_sh[wave]);
            float acc = 0.0f;
#pragma unroll
            for (int t = 0; t < DIMS / 4; ++t) {
                const float4 a = xn4[t];
                const float4 b = nrow[t];
                acc += a.x * b.x + a.y * b.y + a.z * b.z + a.w * b.w;
            }
            s = 1.0f / (1.0f + expf(-acc));
        }
        v = node_epilogue(s, lane, N, *h_ptr);
    }

    v += __shfl_xor(v, 1);
    v += __shfl_xor(v, 2);
    v += __shfl_xor(v, 4);
    v += __shfl_xor(v, 8);
    v += __shfl_xor(v, 16);
    v += __shfl_xor(v, 32);

    if (lane == 0) wsum[wave] = v;
    __syncthreads();
    if (threadIdx.x == 0)
        ws[blockIdx.x] = wsum[0] + wsum[1] + wsum[2] + wsum[3];
}

// ---------------------------------------------------------------------------
// Kernel 2: deterministic single-block reduction of per-block partials.
// ---------------------------------------------------------------------------
__global__ __launch_bounds__(256) void reduce_final(
    const float* __restrict__ ws, float* __restrict__ out, int nparts)
{
    __shared__ float sm[WAVES_PER_BLOCK];
    float acc = 0.0f;
    for (int i = threadIdx.x; i < nparts; i += 256) acc += ws[i];

    acc += __shfl_xor(acc, 1);
    acc += __shfl_xor(acc, 2);
    acc += __shfl_xor(acc, 4);
    acc += __shfl_xor(acc, 8);
    acc += __shfl_xor(acc, 16);
    acc += __shfl_xor(acc, 32);

    const int wave = threadIdx.x >> 6;
    const int lane = threadIdx.x & 63;
    if (lane == 0) sm[wave] = acc;
    __syncthreads();
    if (threadIdx.x == 0)
        out[0] = sm[0] + sm[1] + sm[2] + sm[3];
}

extern "C" void kernel_launch(void* const* d_in, const int* in_sizes, int n_in,
                              void* d_out, int out_size, void* d_ws, size_t ws_size,
                              hipStream_t stream) {
    const float* x   = (const float*)d_in[0];
    const int*   pos = (const int*)d_in[1];
    const int*   neg = (const int*)d_in[2];
    const int*   h   = (const int*)d_in[3];

    const int N = in_sizes[0] / DIMS;  // 50000
    const int nblocks = (N + WAVES_PER_BLOCK - 1) / WAVES_PER_BLOCK;

    const size_t x8_bytes = (size_t)N * DIMS;  // 6.4 MB (1 B/elem)
    const size_t need     = x8_bytes + (size_t)nblocks * sizeof(float);

    if (ws_size >= need) {
        unsigned int* x8 = (unsigned int*)d_ws;
        float* partials  = (float*)((char*)d_ws + x8_bytes);  // 128B-aligned
        const int n8 = N * DIMS / 8;
        convert_f32_to_f8<<<2048, 256, 0, stream>>>(x, x8, n8);
        node_loss_partial_f8v3<<<nblocks, 256, 0, stream>>>(x, x8, pos, neg, h, partials, N);
        reduce_final<<<1, 256, 0, stream>>>(partials, (float*)d_out, nblocks);
    } else {
        float* partials = (float*)d_ws;
        node_loss_partial_f32<<<nblocks, 256, 0, stream>>>(x, pos, neg, h, partials, N);
        reduce_final<<<1, 256, 0, stream>>>(partials, (float*)d_out, nblocks);
    }
}